// Round 1
// baseline (28005.252 us; speedup 1.0000x reference)
//
#include <hip/hip_runtime.h>
#include <cstdint>
#include <cstddef>

namespace {

constexpr int kN = 50000;   // nodes
constexpr int kE = 800000;  // edges
constexpr float kInv3 = 0.57735026918962576451f; // 1/sqrt(3)
constexpr float kInv2 = 0.70710678118654752440f; // 1/sqrt(2)

__device__ __forceinline__ float bcast(float v, int k) {
  return __int_as_float(__builtin_amdgcn_readlane(__float_as_int(v), k));
}
__device__ __forceinline__ float silu(float x) {
  return x / (1.0f + __expf(-x));
}

// ---------------------------------------------------------------------------
// K1: h0 = x0 @ pre_W0 ; h1[:,:,m] = x1[:,:,m] @ pre_W1
// hcomb[n][c] = (h0, h1x, h1y, h1z).  One wave per node, lane = channel.
// ---------------------------------------------------------------------------
__global__ __launch_bounds__(256) void k_pre(const float* __restrict__ nf,
                                             const float* __restrict__ W0,
                                             const float* __restrict__ W1,
                                             float4* __restrict__ hcomb) {
  __shared__ float sW[8192];  // [0..4096) = pre_W0, [4096..8192) = pre_W1
  for (int i = threadIdx.x; i < 8192; i += 256)
    sW[i] = (i < 4096) ? W0[i] : W1[i - 4096];
  __syncthreads();

  const int wid = threadIdx.x >> 6, lane = threadIdx.x & 63;
  const int n = blockIdx.x * 4 + wid;
  if (n >= kN) return;
  const float* row = nf + (size_t)n * 256;
  const float v0 = row[lane];
  const float vx = row[64 + 3 * lane];
  const float vy = row[64 + 3 * lane + 1];
  const float vz = row[64 + 3 * lane + 2];
  float a0 = 0.f, ax = 0.f, ay = 0.f, az = 0.f;
#pragma unroll
  for (int k = 0; k < 64; ++k) {
    const float w0 = sW[k * 64 + lane];
    const float w1 = sW[4096 + k * 64 + lane];
    a0 = fmaf(bcast(v0, k), w0, a0);
    ax = fmaf(bcast(vx, k), w1, ax);
    ay = fmaf(bcast(vy, k), w1, ay);
    az = fmaf(bcast(vz, k), w1, az);
  }
  hcomb[(size_t)n * 64 + lane] = make_float4(a0, ax, ay, az);
}

// ---------------------------------------------------------------------------
// CSR build: histogram of receivers -> exclusive scan -> scatter edge ids.
// ---------------------------------------------------------------------------
__global__ void k_hist(const int* __restrict__ ei, int* __restrict__ cnt) {
  const int e = blockIdx.x * blockDim.x + threadIdx.x;
  if (e < kE) atomicAdd(&cnt[ei[kE + e]], 1);
}

__global__ __launch_bounds__(1024) void k_scan(const int* __restrict__ cnt,
                                               int* __restrict__ starts) {
  __shared__ int sh[1024];
  const int t = threadIdx.x;
  constexpr int CH = 49;  // 1024*49 >= 50000
  const int base = t * CH;
  int s = 0;
  for (int i = 0; i < CH; ++i) {
    const int idx = base + i;
    if (idx < kN) s += cnt[idx];
  }
  sh[t] = s;
  __syncthreads();
  for (int off = 1; off < 1024; off <<= 1) {
    const int v = sh[t];
    const int o = (t >= off) ? sh[t - off] : 0;
    __syncthreads();
    sh[t] = v + o;
    __syncthreads();
  }
  int run = sh[t] - s;  // exclusive prefix of this thread's chunk
  for (int i = 0; i < CH; ++i) {
    const int idx = base + i;
    if (idx < kN) {
      starts[idx] = run;
      run += cnt[idx];
    }
  }
}

__global__ void k_scatter(const int* __restrict__ ei, int* __restrict__ cursor,
                          int* __restrict__ eids) {
  const int e = blockIdx.x * blockDim.x + threadIdx.x;
  if (e < kE) {
    const int pos = atomicAdd(&cursor[ei[kE + e]], 1);
    eids[pos] = e;
  }
}

// ---------------------------------------------------------------------------
// K2: per-receiving-node aggregation. One wave per node (lane = channel).
// For each incoming edge: radial MLP (8->64->64->320) + message, accumulate.
// MLP weights staged in 98KB dynamic LDS. No atomics, no t-zeroing needed.
// ---------------------------------------------------------------------------
__global__ __launch_bounds__(1024, 4) void k_edge(
    const float* __restrict__ rb, const float* __restrict__ sph,
    const int* __restrict__ ei, const int* __restrict__ eids,
    const int* __restrict__ ends, const int* __restrict__ cnts,
    const float* __restrict__ W1, const float* __restrict__ W2,
    const float* __restrict__ W3, const float4* __restrict__ hcomb,
    float4* __restrict__ tcomb) {
  extern __shared__ float sm[];
  float* sW1 = sm;          // 512
  float* sW2 = sm + 512;    // 4096
  float* sW3 = sm + 4608;   // 20480 -> total 25088 floats = 98KB
  for (int i = threadIdx.x; i < 25088; i += 1024) {
    float v;
    if (i < 512) v = W1[i];
    else if (i < 4608) v = W2[i - 512];
    else v = W3[i - 4608];
    sm[i] = v;
  }
  __syncthreads();

  const int lane = threadIdx.x & 63;
  const int gw = blockIdx.x * 16 + (threadIdx.x >> 6);
  for (int n = gw; n < kN; n += 256 * 16) {
    const int end = ends[n];
    const int cn = cnts[n];
    float a0 = 0.f, axx = 0.f, ayy = 0.f, azz = 0.f;
    for (int ii = end - cn; ii < end; ++ii) {
      const int e = eids[ii];
      const int sid = ei[e];
      const float4 r0 = *(const float4*)(rb + (size_t)e * 8);
      const float4 r1 = *(const float4*)(rb + (size_t)e * 8 + 4);
      const float4 sv = *(const float4*)(sph + (size_t)e * 4);
      const float4 h = hcomb[(size_t)sid * 64 + lane];

      // layer 1 (8 -> 64), lane = hidden unit
      float acc = r0.x * sW1[lane];
      acc = fmaf(r0.y, sW1[64 + lane], acc);
      acc = fmaf(r0.z, sW1[128 + lane], acc);
      acc = fmaf(r0.w, sW1[192 + lane], acc);
      acc = fmaf(r1.x, sW1[256 + lane], acc);
      acc = fmaf(r1.y, sW1[320 + lane], acc);
      acc = fmaf(r1.z, sW1[384 + lane], acc);
      acc = fmaf(r1.w, sW1[448 + lane], acc);
      const float h1 = silu(acc);

      // layer 2 (64 -> 64)
      float acc2 = 0.f;
#pragma unroll
      for (int k = 0; k < 64; ++k)
        acc2 = fmaf(bcast(h1, k), sW2[k * 64 + lane], acc2);
      const float h2 = silu(acc2);

      // layer 3 (64 -> 5x64), lane = channel
      float w0 = 0.f, w1v = 0.f, w2v = 0.f, w3v = 0.f, w4v = 0.f;
#pragma unroll
      for (int k = 0; k < 64; ++k) {
        const float hk = bcast(h2, k);
        const float* p = sW3 + k * 320 + lane;
        w0 = fmaf(hk, p[0], w0);
        w1v = fmaf(hk, p[64], w1v);
        w2v = fmaf(hk, p[128], w2v);
        w3v = fmaf(hk, p[192], w3v);
        w4v = fmaf(hk, p[256], w4v);
      }

      // message
      const float y0 = sv.x;
      const float dot = h.y * sv.y + h.z * sv.z + h.w * sv.w;
      const float m0 = w0 * h.x * y0 + w1v * kInv3 * dot;
      const float cx = h.z * sv.w - h.w * sv.z;
      const float cy = h.w * sv.y - h.y * sv.w;
      const float cz = h.y * sv.z - h.z * sv.y;
      const float t2 = w2v * h.x;
      const float c4 = w4v * kInv2;
      const float w3y0 = w3v * y0;
      a0 += m0;
      axx += t2 * sv.y + w3y0 * h.y + c4 * cx;
      ayy += t2 * sv.z + w3y0 * h.z + c4 * cy;
      azz += t2 * sv.w + w3y0 * h.w + c4 * cz;
    }
    tcomb[(size_t)n * 64 + lane] = make_float4(a0, axx, ayy, azz);
  }
}

// ---------------------------------------------------------------------------
// K3a: self-connection einsums ->
//   sc0[n,c] = sum_{k,a} x0[n,k] attr[n,a] sc_W0[k,a,c]
//   sc1[n,c,m] = sum_{k,a} x1[n,k,m] attr[n,a] sc_W1[k,a,c]
// 8-k LDS-tiled chunks of the (64,10,64) weight tensors.
// ---------------------------------------------------------------------------
__global__ __launch_bounds__(1024, 8) void k_sc(const float* __restrict__ nf,
                                                const float* __restrict__ attrs,
                                                const float* __restrict__ scW0,
                                                const float* __restrict__ scW1,
                                                float4* __restrict__ scout) {
  extern __shared__ float sm[];  // 2 * 5120 floats = 40KB
  float* s0 = sm;
  float* s1 = sm + 5120;
  const int lane = threadIdx.x & 63, wid = threadIdx.x >> 6;
  for (int nb = blockIdx.x * 16; nb < kN; nb += 512 * 16) {
    const int n = nb + wid;
    const bool act = (n < kN);
    float attrv[10];
    float xr0 = 0.f, x1x = 0.f, x1y = 0.f, x1z = 0.f;
    if (act) {
      const float* row = nf + (size_t)n * 256;
      xr0 = row[lane];
      x1x = row[64 + 3 * lane];
      x1y = row[64 + 3 * lane + 1];
      x1z = row[64 + 3 * lane + 2];
#pragma unroll
      for (int a = 0; a < 10; ++a) attrv[a] = attrs[(size_t)n * 10 + a];
    } else {
#pragma unroll
      for (int a = 0; a < 10; ++a) attrv[a] = 0.f;
    }
    float a0 = 0.f, axx = 0.f, ayy = 0.f, azz = 0.f;
    for (int ck = 0; ck < 8; ++ck) {
      __syncthreads();  // protect LDS from previous chunk's readers
      for (int i = threadIdx.x; i < 5120; i += 1024) {
        s0[i] = scW0[ck * 5120 + i];
        s1[i] = scW1[ck * 5120 + i];
      }
      __syncthreads();
      if (act) {
#pragma unroll
        for (int k = 0; k < 8; ++k) {
          const int kg = ck * 8 + k;
          const float x0k = bcast(xr0, kg);
          const float xxk = bcast(x1x, kg);
          const float xyk = bcast(x1y, kg);
          const float xzk = bcast(x1z, kg);
          float t0 = 0.f, t1 = 0.f;
#pragma unroll
          for (int a = 0; a < 10; ++a) {
            t0 = fmaf(attrv[a], s0[k * 640 + a * 64 + lane], t0);
            t1 = fmaf(attrv[a], s1[k * 640 + a * 64 + lane], t1);
          }
          a0 = fmaf(x0k, t0, a0);
          axx = fmaf(xxk, t1, axx);
          ayy = fmaf(xyk, t1, ayy);
          azz = fmaf(xzk, t1, azz);
        }
      }
    }
    if (act) scout[(size_t)n * 64 + lane] = make_float4(a0, axx, ayy, azz);
  }
}

// ---------------------------------------------------------------------------
// K3b: lin transforms, attribute-gated nonlinearity, + self-connection,
// final fin transforms, write concatenated output.
// ---------------------------------------------------------------------------
__global__ __launch_bounds__(1024, 4) void k_post(
    const float* __restrict__ nf, const float* __restrict__ attrs,
    const float* __restrict__ lin0, const float* __restrict__ lin1,
    const float* __restrict__ c0w, const float* __restrict__ c1w,
    const float* __restrict__ fin0, const float* __restrict__ fin1,
    const float4* __restrict__ tcomb, const float4* __restrict__ scout,
    float* __restrict__ out) {
  extern __shared__ float sm[];  // 4 * 4096 floats = 64KB
  float* sl0 = sm;
  float* sl1 = sm + 4096;
  float* sf0 = sm + 8192;
  float* sf1 = sm + 12288;
  __shared__ float sc0[1920];  // c0_w (10,3,64)
  __shared__ float sc1[1280];  // c1_w (10,2,64)
  for (int i = threadIdx.x; i < 4096; i += 1024) {
    sl0[i] = lin0[i];
    sl1[i] = lin1[i];
    sf0[i] = fin0[i];
    sf1[i] = fin1[i];
  }
  for (int i = threadIdx.x; i < 1920; i += 1024) sc0[i] = c0w[i];
  for (int i = threadIdx.x; i < 1280; i += 1024) sc1[i] = c1w[i];
  __syncthreads();

  const int lane = threadIdx.x & 63;
  for (int n = blockIdx.x * 16 + (threadIdx.x >> 6); n < kN; n += 512 * 16) {
    const float4 t = tcomb[(size_t)n * 64 + lane];
    float b0 = 0.f, bx = 0.f, by = 0.f, bz = 0.f;
#pragma unroll
    for (int k = 0; k < 64; ++k) {
      const float w0 = sl0[k * 64 + lane];
      const float w1 = sl1[k * 64 + lane];
      b0 = fmaf(bcast(t.x, k), w0, b0);
      bx = fmaf(bcast(t.y, k), w1, bx);
      by = fmaf(bcast(t.z, k), w1, by);
      bz = fmaf(bcast(t.w, k), w1, bz);
    }
    float cw00 = 0.f, cw01 = 0.f, cw02 = 0.f, cw10 = 0.f, cw11 = 0.f;
#pragma unroll
    for (int a = 0; a < 10; ++a) {
      const float av = attrs[(size_t)n * 10 + a];
      cw00 = fmaf(av, sc0[a * 192 + lane], cw00);
      cw01 = fmaf(av, sc0[a * 192 + 64 + lane], cw01);
      cw02 = fmaf(av, sc0[a * 192 + 128 + lane], cw02);
      cw10 = fmaf(av, sc1[a * 128 + lane], cw10);
      cw11 = fmaf(av, sc1[a * 128 + 64 + lane], cw11);
    }
    const float4 sc = scout[(size_t)n * 64 + lane];
    const float o0 = cw00 * b0 + cw01 * b0 * b0 +
                     cw02 * (bx * bx + by * by + bz * bz) + sc.x;
    const float o1x = cw10 * bx + cw11 * b0 * bx + sc.y;
    const float o1y = cw10 * by + cw11 * b0 * by + sc.z;
    const float o1z = cw10 * bz + cw11 * b0 * bz + sc.w;
    float f0 = 0.f, fx = 0.f, fy = 0.f, fz = 0.f;
#pragma unroll
    for (int k = 0; k < 64; ++k) {
      const float w0 = sf0[k * 64 + lane];
      const float w1 = sf1[k * 64 + lane];
      f0 = fmaf(bcast(o0, k), w0, f0);
      fx = fmaf(bcast(o1x, k), w1, fx);
      fy = fmaf(bcast(o1y, k), w1, fy);
      fz = fmaf(bcast(o1z, k), w1, fz);
    }
    float* orow = out + (size_t)n * 256;
    orow[lane] = f0;
    orow[64 + 3 * lane] = fx;
    orow[64 + 3 * lane + 1] = fy;
    orow[64 + 3 * lane + 2] = fz;
  }
}

}  // namespace

extern "C" void kernel_launch(void* const* d_in, const int* in_sizes, int n_in,
                              void* d_out, int out_size, void* d_ws,
                              size_t ws_size, hipStream_t stream) {
  (void)in_sizes; (void)n_in; (void)out_size; (void)ws_size;
  const float* nf = (const float*)d_in[0];
  const float* attrs = (const float*)d_in[1];
  const float* sph = (const float*)d_in[2];
  const float* rb = (const float*)d_in[3];
  const int* ei = (const int*)d_in[4];
  const float* preW0 = (const float*)d_in[5];
  const float* preW1 = (const float*)d_in[6];
  const float* mW1 = (const float*)d_in[7];
  const float* mW2 = (const float*)d_in[8];
  const float* mW3 = (const float*)d_in[9];
  const float* lin0 = (const float*)d_in[10];
  const float* lin1 = (const float*)d_in[11];
  const float* c0w = (const float*)d_in[12];
  const float* c1w = (const float*)d_in[13];
  const float* scW0 = (const float*)d_in[14];
  const float* scW1 = (const float*)d_in[15];
  const float* fin0 = (const float*)d_in[16];
  const float* fin1 = (const float*)d_in[17];
  float* out = (float*)d_out;

  char* ws = (char*)d_ws;
  float4* hcomb = (float4*)ws;                    // 51.2MB (reused as scout)
  float4* tcomb = (float4*)(ws + 51200000);       // 51.2MB
  int* cnts = (int*)(ws + 102400000);             // 200KB
  int* starts = (int*)(ws + 102600000);           // 200KB (becomes ends)
  int* eids = (int*)(ws + 102800000);             // 3.2MB
  float4* scout = hcomb;  // safe: k_edge (last hcomb reader) precedes k_sc

  hipMemsetAsync(cnts, 0, kN * sizeof(int), stream);

  k_pre<<<(kN + 3) / 4, 256, 0, stream>>>(nf, preW0, preW1, hcomb);
  k_hist<<<(kE + 255) / 256, 256, 0, stream>>>(ei, cnts);
  k_scan<<<1, 1024, 0, stream>>>(cnts, starts);
  k_scatter<<<(kE + 255) / 256, 256, 0, stream>>>(ei, starts, eids);

  hipFuncSetAttribute((const void*)k_edge,
                      hipFuncAttributeMaxDynamicSharedMemorySize, 25088 * 4);
  k_edge<<<256, 1024, 25088 * 4, stream>>>(rb, sph, ei, eids, starts, cnts,
                                           mW1, mW2, mW3, hcomb, tcomb);

  hipFuncSetAttribute((const void*)k_sc,
                      hipFuncAttributeMaxDynamicSharedMemorySize, 10240 * 4);
  k_sc<<<512, 1024, 10240 * 4, stream>>>(nf, attrs, scW0, scW1, scout);

  hipFuncSetAttribute((const void*)k_post,
                      hipFuncAttributeMaxDynamicSharedMemorySize, 16384 * 4);
  k_post<<<512, 1024, 16384 * 4, stream>>>(nf, attrs, lin0, lin1, c0w, c1w,
                                           fin0, fin1, tcomb, scout, out);
}

// Round 2
// 3666.066 us; speedup vs baseline: 7.6390x; 7.6390x over previous
//
#include <hip/hip_runtime.h>
#include <cstdint>
#include <cstddef>

namespace {

constexpr int kN = 50000;   // nodes
constexpr int kE = 800000;  // edges
constexpr float kInv3 = 0.57735026918962576451f; // 1/sqrt(3)
constexpr float kInv2 = 0.70710678118654752440f; // 1/sqrt(2)

__device__ __forceinline__ float bcast(float v, int k) {
  return __int_as_float(__builtin_amdgcn_readlane(__float_as_int(v), k));
}
__device__ __forceinline__ int bcasti(int v, int k) {
  return __builtin_amdgcn_readlane(v, k);
}
__device__ __forceinline__ float silu(float x) {
  return x / (1.0f + __expf(-x));
}

// ---------------------------------------------------------------------------
// K1: h0 = x0 @ pre_W0 ; h1[:,:,m] = x1[:,:,m] @ pre_W1
// hcomb[n][c] = (h0, h1x, h1y, h1z).  One wave per node, lane = channel.
// ---------------------------------------------------------------------------
__global__ __launch_bounds__(256) void k_pre(const float* __restrict__ nf,
                                             const float* __restrict__ W0,
                                             const float* __restrict__ W1,
                                             float4* __restrict__ hcomb) {
  __shared__ float sW[8192];  // [0..4096) = pre_W0, [4096..8192) = pre_W1
  for (int i = threadIdx.x; i < 8192; i += 256)
    sW[i] = (i < 4096) ? W0[i] : W1[i - 4096];
  __syncthreads();

  const int wid = threadIdx.x >> 6, lane = threadIdx.x & 63;
  const int n = blockIdx.x * 4 + wid;
  if (n >= kN) return;
  const float* row = nf + (size_t)n * 256;
  const float v0 = row[lane];
  const float vx = row[64 + 3 * lane];
  const float vy = row[64 + 3 * lane + 1];
  const float vz = row[64 + 3 * lane + 2];
  float a0 = 0.f, ax = 0.f, ay = 0.f, az = 0.f;
#pragma unroll
  for (int k = 0; k < 64; ++k) {
    const float w0 = sW[k * 64 + lane];
    const float w1 = sW[4096 + k * 64 + lane];
    a0 = fmaf(bcast(v0, k), w0, a0);
    ax = fmaf(bcast(vx, k), w1, ax);
    ay = fmaf(bcast(vy, k), w1, ay);
    az = fmaf(bcast(vz, k), w1, az);
  }
  hcomb[(size_t)n * 64 + lane] = make_float4(a0, ax, ay, az);
}

// ---------------------------------------------------------------------------
// CSR build: histogram of receivers -> exclusive scan -> scatter edge ids.
// ---------------------------------------------------------------------------
__global__ void k_hist(const int* __restrict__ ei, int* __restrict__ cnt) {
  const int e = blockIdx.x * blockDim.x + threadIdx.x;
  if (e < kE) atomicAdd(&cnt[ei[kE + e]], 1);
}

__global__ __launch_bounds__(1024) void k_scan(const int* __restrict__ cnt,
                                               int* __restrict__ starts) {
  __shared__ int sh[1024];
  const int t = threadIdx.x;
  constexpr int CH = 49;  // 1024*49 >= 50000
  const int base = t * CH;
  int s = 0;
  for (int i = 0; i < CH; ++i) {
    const int idx = base + i;
    if (idx < kN) s += cnt[idx];
  }
  sh[t] = s;
  __syncthreads();
  for (int off = 1; off < 1024; off <<= 1) {
    const int v = sh[t];
    const int o = (t >= off) ? sh[t - off] : 0;
    __syncthreads();
    sh[t] = v + o;
    __syncthreads();
  }
  int run = sh[t] - s;  // exclusive prefix of this thread's chunk
  for (int i = 0; i < CH; ++i) {
    const int idx = base + i;
    if (idx < kN) {
      starts[idx] = run;
      run += cnt[idx];
    }
  }
}

__global__ void k_scatter(const int* __restrict__ ei, int* __restrict__ cursor,
                          int* __restrict__ eids) {
  const int e = blockIdx.x * blockDim.x + threadIdx.x;
  if (e < kE) {
    const int pos = atomicAdd(&cursor[ei[kE + e]], 1);
    eids[pos] = e;
  }
}

// ---------------------------------------------------------------------------
// K2: per-receiving-node aggregation. One wave per node (lane = channel).
// Edge scalars are batch-loaded one-lane-per-edge (coalesced / true gather),
// then broadcast via v_readlane — no wave-uniform 64-lane global loads.
// W2/W3 stored transposed+XOR-swizzled in LDS -> conflict-free ds_read_b128.
// ---------------------------------------------------------------------------
__global__ __launch_bounds__(1024, 4) void k_edge(
    const float* __restrict__ rb, const float* __restrict__ sph,
    const int* __restrict__ ei, const int* __restrict__ eids,
    const int* __restrict__ ends, const int* __restrict__ cnts,
    const float* __restrict__ W1, const float* __restrict__ W2,
    const float* __restrict__ W3, const float4* __restrict__ hcomb,
    float4* __restrict__ tcomb) {
  extern __shared__ float sm[];
  // layout: [0..512)  W1 as-is ([r][c])
  //         [512..4608) W2 transposed+swizzled: (k,c) -> 512 + c*64 + ((k>>2)^(c&7))*4 + (k&3)
  //         [4608..25088) W3 as 5 blocks q: (k,q,c) -> 4608 + q*4096 + c*64 + ((k>>2)^(c&7))*4 + (k&3)
  for (int i = threadIdx.x; i < 25088; i += 1024) {
    float v;
    int dst;
    if (i < 512) {
      v = W1[i];
      dst = i;
    } else if (i < 4608) {
      const int j = i - 512;
      const int k = j >> 6, c = j & 63;
      v = W2[j];
      dst = 512 + c * 64 + (((k >> 2) ^ (c & 7)) << 2) + (k & 3);
    } else {
      const int j = i - 4608;
      const int k = j / 320, r = j - k * 320;
      const int q = r >> 6, c = r & 63;
      v = W3[j];
      dst = 4608 + q * 4096 + c * 64 + (((k >> 2) ^ (c & 7)) << 2) + (k & 3);
    }
    sm[dst] = v;
  }
  __syncthreads();

  const float* sW1 = sm;
  const float* sW2 = sm + 512;
  const float* sW3 = sm + 4608;
  const int lane = threadIdx.x & 63;
  const int gw = blockIdx.x * 16 + (threadIdx.x >> 6);
  const int rowoff = lane * 64;        // word offset of this lane's W2T/W3T row
  const int lsw = lane & 7;            // swizzle key

  for (int n = gw; n < kN; n += 256 * 16) {
    int tmp = 0;
    if (lane == 0) tmp = ends[n];
    else if (lane == 1) tmp = cnts[n];
    const int end = bcasti(tmp, 0);
    const int cn = bcasti(tmp, 1);
    float a0 = 0.f, axx = 0.f, ayy = 0.f, azz = 0.f;

    for (int base = end - cn; base < end; base += 64) {
      const int m = min(64, end - base);
      int sidv = 0;
      float4 r0v = make_float4(0.f, 0.f, 0.f, 0.f);
      float4 r1v = r0v, svv = r0v;
      if (lane < m) {
        const int e = eids[base + lane];
        sidv = ei[e];
        r0v = *(const float4*)(rb + (size_t)e * 8);
        r1v = *(const float4*)(rb + (size_t)e * 8 + 4);
        svv = *(const float4*)(sph + (size_t)e * 4);
      }
      const int sid0 = bcasti(sidv, 0);
      float4 h = hcomb[(size_t)sid0 * 64 + lane];

      for (int j = 0; j < m; ++j) {
        float4 hn = h;
        if (j + 1 < m) {
          const int sn = bcasti(sidv, j + 1);
          hn = hcomb[(size_t)sn * 64 + lane];
        }
        // broadcast edge scalars from the holder lane
        const float e0 = bcast(r0v.x, j), e1 = bcast(r0v.y, j);
        const float e2 = bcast(r0v.z, j), e3 = bcast(r0v.w, j);
        const float e4 = bcast(r1v.x, j), e5 = bcast(r1v.y, j);
        const float e6 = bcast(r1v.z, j), e7 = bcast(r1v.w, j);
        const float y0 = bcast(svv.x, j), y1 = bcast(svv.y, j);
        const float y2 = bcast(svv.z, j), y3 = bcast(svv.w, j);

        // layer 1 (8 -> 64), lane = hidden unit
        float acc = e0 * sW1[lane];
        acc = fmaf(e1, sW1[64 + lane], acc);
        acc = fmaf(e2, sW1[128 + lane], acc);
        acc = fmaf(e3, sW1[192 + lane], acc);
        acc = fmaf(e4, sW1[256 + lane], acc);
        acc = fmaf(e5, sW1[320 + lane], acc);
        acc = fmaf(e6, sW1[384 + lane], acc);
        acc = fmaf(e7, sW1[448 + lane], acc);
        const float h1 = silu(acc);

        // layer 2 (64 -> 64): b128 swizzled reads, readlane broadcast of h1
        float acc2 = 0.f;
#pragma unroll
        for (int k4 = 0; k4 < 16; ++k4) {
          const float4 w = *(const float4*)(sW2 + rowoff + ((k4 ^ lsw) << 2));
          acc2 = fmaf(bcast(h1, 4 * k4 + 0), w.x, acc2);
          acc2 = fmaf(bcast(h1, 4 * k4 + 1), w.y, acc2);
          acc2 = fmaf(bcast(h1, 4 * k4 + 2), w.z, acc2);
          acc2 = fmaf(bcast(h1, 4 * k4 + 3), w.w, acc2);
        }
        const float h2 = silu(acc2);

        // layer 3 (64 -> 5x64), lane = channel
        float w0 = 0.f, w1v = 0.f, w2v = 0.f, w3v = 0.f, w4v = 0.f;
#pragma unroll 4
        for (int k4 = 0; k4 < 16; ++k4) {
          const int off = rowoff + ((k4 ^ lsw) << 2);
          const float4 p0 = *(const float4*)(sW3 + off);
          const float4 p1 = *(const float4*)(sW3 + 4096 + off);
          const float4 p2 = *(const float4*)(sW3 + 8192 + off);
          const float4 p3 = *(const float4*)(sW3 + 12288 + off);
          const float4 p4 = *(const float4*)(sW3 + 16384 + off);
          const float k0 = bcast(h2, 4 * k4 + 0);
          const float k1 = bcast(h2, 4 * k4 + 1);
          const float k2 = bcast(h2, 4 * k4 + 2);
          const float k3 = bcast(h2, 4 * k4 + 3);
          w0 = fmaf(k0, p0.x, w0); w0 = fmaf(k1, p0.y, w0);
          w0 = fmaf(k2, p0.z, w0); w0 = fmaf(k3, p0.w, w0);
          w1v = fmaf(k0, p1.x, w1v); w1v = fmaf(k1, p1.y, w1v);
          w1v = fmaf(k2, p1.z, w1v); w1v = fmaf(k3, p1.w, w1v);
          w2v = fmaf(k0, p2.x, w2v); w2v = fmaf(k1, p2.y, w2v);
          w2v = fmaf(k2, p2.z, w2v); w2v = fmaf(k3, p2.w, w2v);
          w3v = fmaf(k0, p3.x, w3v); w3v = fmaf(k1, p3.y, w3v);
          w3v = fmaf(k2, p3.z, w3v); w3v = fmaf(k3, p3.w, w3v);
          w4v = fmaf(k0, p4.x, w4v); w4v = fmaf(k1, p4.y, w4v);
          w4v = fmaf(k2, p4.z, w4v); w4v = fmaf(k3, p4.w, w4v);
        }

        // message
        const float dot = h.y * y1 + h.z * y2 + h.w * y3;
        const float m0 = w0 * h.x * y0 + w1v * kInv3 * dot;
        const float cx = h.z * y3 - h.w * y2;
        const float cy = h.w * y1 - h.y * y3;
        const float cz = h.y * y2 - h.z * y1;
        const float t2 = w2v * h.x;
        const float c4 = w4v * kInv2;
        const float w3y0 = w3v * y0;
        a0 += m0;
        axx += t2 * y1 + w3y0 * h.y + c4 * cx;
        ayy += t2 * y2 + w3y0 * h.z + c4 * cy;
        azz += t2 * y3 + w3y0 * h.w + c4 * cz;
        h = hn;
      }
    }
    tcomb[(size_t)n * 64 + lane] = make_float4(a0, axx, ayy, azz);
  }
}

// ---------------------------------------------------------------------------
// K3a: self-connection einsums (8-k LDS-tiled chunks of the weight tensors).
// ---------------------------------------------------------------------------
__global__ __launch_bounds__(1024, 8) void k_sc(const float* __restrict__ nf,
                                                const float* __restrict__ attrs,
                                                const float* __restrict__ scW0,
                                                const float* __restrict__ scW1,
                                                float4* __restrict__ scout) {
  extern __shared__ float sm[];  // 2 * 5120 floats = 40KB
  float* s0 = sm;
  float* s1 = sm + 5120;
  const int lane = threadIdx.x & 63, wid = threadIdx.x >> 6;
  for (int nb = blockIdx.x * 16; nb < kN; nb += 512 * 16) {
    const int n = nb + wid;
    const bool act = (n < kN);
    float xr0 = 0.f, x1x = 0.f, x1y = 0.f, x1z = 0.f;
    float avl = 0.f;
    if (act) {
      const float* row = nf + (size_t)n * 256;
      xr0 = row[lane];
      x1x = row[64 + 3 * lane];
      x1y = row[64 + 3 * lane + 1];
      x1z = row[64 + 3 * lane + 2];
      if (lane < 10) avl = attrs[(size_t)n * 10 + lane];
    }
    float attrv[10];
#pragma unroll
    for (int a = 0; a < 10; ++a) attrv[a] = bcast(avl, a);
    float a0 = 0.f, axx = 0.f, ayy = 0.f, azz = 0.f;
    for (int ck = 0; ck < 8; ++ck) {
      __syncthreads();  // protect LDS from previous chunk's readers
      for (int i = threadIdx.x; i < 5120; i += 1024) {
        s0[i] = scW0[ck * 5120 + i];
        s1[i] = scW1[ck * 5120 + i];
      }
      __syncthreads();
      if (act) {
#pragma unroll
        for (int k = 0; k < 8; ++k) {
          const int kg = ck * 8 + k;
          const float x0k = bcast(xr0, kg);
          const float xxk = bcast(x1x, kg);
          const float xyk = bcast(x1y, kg);
          const float xzk = bcast(x1z, kg);
          float t0 = 0.f, t1 = 0.f;
#pragma unroll
          for (int a = 0; a < 10; ++a) {
            t0 = fmaf(attrv[a], s0[k * 640 + a * 64 + lane], t0);
            t1 = fmaf(attrv[a], s1[k * 640 + a * 64 + lane], t1);
          }
          a0 = fmaf(x0k, t0, a0);
          axx = fmaf(xxk, t1, axx);
          ayy = fmaf(xyk, t1, ayy);
          azz = fmaf(xzk, t1, azz);
        }
      }
    }
    if (act) scout[(size_t)n * 64 + lane] = make_float4(a0, axx, ayy, azz);
  }
}

// ---------------------------------------------------------------------------
// K3b: lin transforms, gated nonlinearity, + self-connection, fin transforms.
// ---------------------------------------------------------------------------
__global__ __launch_bounds__(1024, 4) void k_post(
    const float* __restrict__ nf, const float* __restrict__ attrs,
    const float* __restrict__ lin0, const float* __restrict__ lin1,
    const float* __restrict__ c0w, const float* __restrict__ c1w,
    const float* __restrict__ fin0, const float* __restrict__ fin1,
    const float4* __restrict__ tcomb, const float4* __restrict__ scout,
    float* __restrict__ out) {
  extern __shared__ float sm[];  // 4 * 4096 floats = 64KB
  float* sl0 = sm;
  float* sl1 = sm + 4096;
  float* sf0 = sm + 8192;
  float* sf1 = sm + 12288;
  __shared__ float sc0[1920];  // c0_w (10,3,64)
  __shared__ float sc1[1280];  // c1_w (10,2,64)
  for (int i = threadIdx.x; i < 4096; i += 1024) {
    sl0[i] = lin0[i];
    sl1[i] = lin1[i];
    sf0[i] = fin0[i];
    sf1[i] = fin1[i];
  }
  for (int i = threadIdx.x; i < 1920; i += 1024) sc0[i] = c0w[i];
  for (int i = threadIdx.x; i < 1280; i += 1024) sc1[i] = c1w[i];
  __syncthreads();

  const int lane = threadIdx.x & 63;
  for (int n = blockIdx.x * 16 + (threadIdx.x >> 6); n < kN; n += 512 * 16) {
    const float4 t = tcomb[(size_t)n * 64 + lane];
    float avl = 0.f;
    if (lane < 10) avl = attrs[(size_t)n * 10 + lane];
    float b0 = 0.f, bx = 0.f, by = 0.f, bz = 0.f;
#pragma unroll
    for (int k = 0; k < 64; ++k) {
      const float w0 = sl0[k * 64 + lane];
      const float w1 = sl1[k * 64 + lane];
      b0 = fmaf(bcast(t.x, k), w0, b0);
      bx = fmaf(bcast(t.y, k), w1, bx);
      by = fmaf(bcast(t.z, k), w1, by);
      bz = fmaf(bcast(t.w, k), w1, bz);
    }
    float cw00 = 0.f, cw01 = 0.f, cw02 = 0.f, cw10 = 0.f, cw11 = 0.f;
#pragma unroll
    for (int a = 0; a < 10; ++a) {
      const float av = bcast(avl, a);
      cw00 = fmaf(av, sc0[a * 192 + lane], cw00);
      cw01 = fmaf(av, sc0[a * 192 + 64 + lane], cw01);
      cw02 = fmaf(av, sc0[a * 192 + 128 + lane], cw02);
      cw10 = fmaf(av, sc1[a * 128 + lane], cw10);
      cw11 = fmaf(av, sc1[a * 128 + 64 + lane], cw11);
    }
    const float4 sc = scout[(size_t)n * 64 + lane];
    const float o0 = cw00 * b0 + cw01 * b0 * b0 +
                     cw02 * (bx * bx + by * by + bz * bz) + sc.x;
    const float o1x = cw10 * bx + cw11 * b0 * bx + sc.y;
    const float o1y = cw10 * by + cw11 * b0 * by + sc.z;
    const float o1z = cw10 * bz + cw11 * b0 * bz + sc.w;
    float f0 = 0.f, fx = 0.f, fy = 0.f, fz = 0.f;
#pragma unroll
    for (int k = 0; k < 64; ++k) {
      const float w0 = sf0[k * 64 + lane];
      const float w1 = sf1[k * 64 + lane];
      f0 = fmaf(bcast(o0, k), w0, f0);
      fx = fmaf(bcast(o1x, k), w1, fx);
      fy = fmaf(bcast(o1y, k), w1, fy);
      fz = fmaf(bcast(o1z, k), w1, fz);
    }
    float* orow = out + (size_t)n * 256;
    orow[lane] = f0;
    orow[64 + 3 * lane] = fx;
    orow[64 + 3 * lane + 1] = fy;
    orow[64 + 3 * lane + 2] = fz;
  }
}

}  // namespace

extern "C" void kernel_launch(void* const* d_in, const int* in_sizes, int n_in,
                              void* d_out, int out_size, void* d_ws,
                              size_t ws_size, hipStream_t stream) {
  (void)in_sizes; (void)n_in; (void)out_size; (void)ws_size;
  const float* nf = (const float*)d_in[0];
  const float* attrs = (const float*)d_in[1];
  const float* sph = (const float*)d_in[2];
  const float* rb = (const float*)d_in[3];
  const int* ei = (const int*)d_in[4];
  const float* preW0 = (const float*)d_in[5];
  const float* preW1 = (const float*)d_in[6];
  const float* mW1 = (const float*)d_in[7];
  const float* mW2 = (const float*)d_in[8];
  const float* mW3 = (const float*)d_in[9];
  const float* lin0 = (const float*)d_in[10];
  const float* lin1 = (const float*)d_in[11];
  const float* c0w = (const float*)d_in[12];
  const float* c1w = (const float*)d_in[13];
  const float* scW0 = (const float*)d_in[14];
  const float* scW1 = (const float*)d_in[15];
  const float* fin0 = (const float*)d_in[16];
  const float* fin1 = (const float*)d_in[17];
  float* out = (float*)d_out;

  char* ws = (char*)d_ws;
  float4* hcomb = (float4*)ws;                    // 51.2MB (reused as scout)
  float4* tcomb = (float4*)(ws + 51200000);       // 51.2MB
  int* cnts = (int*)(ws + 102400000);             // 200KB
  int* starts = (int*)(ws + 102600000);           // 200KB (becomes ends)
  int* eids = (int*)(ws + 102800000);             // 3.2MB
  float4* scout = hcomb;  // safe: k_edge (last hcomb reader) precedes k_sc

  hipMemsetAsync(cnts, 0, kN * sizeof(int), stream);

  k_pre<<<(kN + 3) / 4, 256, 0, stream>>>(nf, preW0, preW1, hcomb);
  k_hist<<<(kE + 255) / 256, 256, 0, stream>>>(ei, cnts);
  k_scan<<<1, 1024, 0, stream>>>(cnts, starts);
  k_scatter<<<(kE + 255) / 256, 256, 0, stream>>>(ei, starts, eids);

  hipFuncSetAttribute((const void*)k_edge,
                      hipFuncAttributeMaxDynamicSharedMemorySize, 25088 * 4);
  k_edge<<<256, 1024, 25088 * 4, stream>>>(rb, sph, ei, eids, starts, cnts,
                                           mW1, mW2, mW3, hcomb, tcomb);

  hipFuncSetAttribute((const void*)k_sc,
                      hipFuncAttributeMaxDynamicSharedMemorySize, 10240 * 4);
  k_sc<<<512, 1024, 10240 * 4, stream>>>(nf, attrs, scW0, scW1, scout);

  hipFuncSetAttribute((const void*)k_post,
                      hipFuncAttributeMaxDynamicSharedMemorySize, 16384 * 4);
  k_post<<<512, 1024, 16384 * 4, stream>>>(nf, attrs, lin0, lin1, c0w, c1w,
                                           fin0, fin1, tcomb, scout, out);
}

// Round 3
// 2156.828 us; speedup vs baseline: 12.9845x; 1.6997x over previous
//
#include <hip/hip_runtime.h>
#include <cstdint>
#include <cstddef>

namespace {

constexpr int kN = 50000;   // nodes
constexpr int kE = 800000;  // edges
constexpr float kInv3 = 0.57735026918962576451f; // 1/sqrt(3)
constexpr float kInv2 = 0.70710678118654752440f; // 1/sqrt(2)

__device__ __forceinline__ float bcast(float v, int k) {
  return __int_as_float(__builtin_amdgcn_readlane(__float_as_int(v), k));
}
__device__ __forceinline__ int bcasti(int v, int k) {
  return __builtin_amdgcn_readlane(v, k);
}
__device__ __forceinline__ float silu(float x) {
  return x / (1.0f + __expf(-x));
}

// ---------------------------------------------------------------------------
// K1: h0 = x0 @ pre_W0 ; h1[:,:,m] = x1[:,:,m] @ pre_W1
// hcomb[n][c] = (h0, h1x, h1y, h1z).  One wave per node, lane = channel.
// Input row loaded as 64 contiguous float4 and redistributed via per-wave LDS.
// ---------------------------------------------------------------------------
__global__ __launch_bounds__(256) void k_pre(const float* __restrict__ nf,
                                             const float* __restrict__ W0,
                                             const float* __restrict__ W1,
                                             float4* __restrict__ hcomb) {
  __shared__ float sW[8192];  // [0..4096) = pre_W0, [4096..8192) = pre_W1
  __shared__ float sbuf[4][256];
  for (int i = threadIdx.x; i < 8192; i += 256)
    sW[i] = (i < 4096) ? W0[i] : W1[i - 4096];
  __syncthreads();

  const int wid = threadIdx.x >> 6, lane = threadIdx.x & 63;
  const int n = blockIdx.x * 4 + wid;
  if (n >= kN) return;
  // coalesced 1KB row load, bounce through LDS to get stride-3 view
  const float4 rv = ((const float4*)nf)[(size_t)n * 64 + lane];
  *(float4*)&sbuf[wid][lane * 4] = rv;
  const float v0 = sbuf[wid][lane];
  const float vx = sbuf[wid][64 + 3 * lane];
  const float vy = sbuf[wid][64 + 3 * lane + 1];
  const float vz = sbuf[wid][64 + 3 * lane + 2];
  float a0 = 0.f, ax = 0.f, ay = 0.f, az = 0.f;
#pragma unroll
  for (int k = 0; k < 64; ++k) {
    const float w0 = sW[k * 64 + lane];
    const float w1 = sW[4096 + k * 64 + lane];
    a0 = fmaf(bcast(v0, k), w0, a0);
    ax = fmaf(bcast(vx, k), w1, ax);
    ay = fmaf(bcast(vy, k), w1, ay);
    az = fmaf(bcast(vz, k), w1, az);
  }
  hcomb[(size_t)n * 64 + lane] = make_float4(a0, ax, ay, az);
}

// ---------------------------------------------------------------------------
// CSR build: histogram of receivers -> exclusive scan -> scatter edge ids.
// ---------------------------------------------------------------------------
__global__ void k_hist(const int* __restrict__ ei, int* __restrict__ cnt) {
  const int e = blockIdx.x * blockDim.x + threadIdx.x;
  if (e < kE) atomicAdd(&cnt[ei[kE + e]], 1);
}

__global__ __launch_bounds__(1024) void k_scan(const int* __restrict__ cnt,
                                               int* __restrict__ starts) {
  __shared__ int sh[1024];
  const int t = threadIdx.x;
  constexpr int CH = 49;  // 1024*49 >= 50000
  const int base = t * CH;
  int s = 0;
  for (int i = 0; i < CH; ++i) {
    const int idx = base + i;
    if (idx < kN) s += cnt[idx];
  }
  sh[t] = s;
  __syncthreads();
  for (int off = 1; off < 1024; off <<= 1) {
    const int v = sh[t];
    const int o = (t >= off) ? sh[t - off] : 0;
    __syncthreads();
    sh[t] = v + o;
    __syncthreads();
  }
  int run = sh[t] - s;  // exclusive prefix of this thread's chunk
  for (int i = 0; i < CH; ++i) {
    const int idx = base + i;
    if (idx < kN) {
      starts[idx] = run;
      run += cnt[idx];
    }
  }
}

__global__ void k_scatter(const int* __restrict__ ei, int* __restrict__ cursor,
                          int* __restrict__ eids) {
  const int e = blockIdx.x * blockDim.x + threadIdx.x;
  if (e < kE) {
    const int pos = atomicAdd(&cursor[ei[kE + e]], 1);
    eids[pos] = e;
  }
}

// ---------------------------------------------------------------------------
// K2: per-receiving-node aggregation. One wave per node (lane = channel).
// Edge scalars batch-loaded one-lane-per-edge, broadcast via v_readlane.
// W2/W3 transposed+XOR-swizzled in LDS -> conflict-free ds_read_b128.
// ---------------------------------------------------------------------------
__global__ __launch_bounds__(1024, 4) void k_edge(
    const float* __restrict__ rb, const float* __restrict__ sph,
    const int* __restrict__ ei, const int* __restrict__ eids,
    const int* __restrict__ ends, const int* __restrict__ cnts,
    const float* __restrict__ W1, const float* __restrict__ W2,
    const float* __restrict__ W3, const float4* __restrict__ hcomb,
    float4* __restrict__ tcomb) {
  extern __shared__ float sm[];
  // layout: [0..512)  W1 as-is ([r][c])
  //         [512..4608) W2T+swz: (k,c) -> 512 + c*64 + ((k>>2)^(c&7))*4 + (k&3)
  //         [4608..25088) W3 5 blocks q: 4608 + q*4096 + c*64 + swz(k,c)
  for (int i = threadIdx.x; i < 25088; i += 1024) {
    float v;
    int dst;
    if (i < 512) {
      v = W1[i];
      dst = i;
    } else if (i < 4608) {
      const int j = i - 512;
      const int k = j >> 6, c = j & 63;
      v = W2[j];
      dst = 512 + c * 64 + (((k >> 2) ^ (c & 7)) << 2) + (k & 3);
    } else {
      const int j = i - 4608;
      const int k = j / 320, r = j - k * 320;
      const int q = r >> 6, c = r & 63;
      v = W3[j];
      dst = 4608 + q * 4096 + c * 64 + (((k >> 2) ^ (c & 7)) << 2) + (k & 3);
    }
    sm[dst] = v;
  }
  __syncthreads();

  const float* sW1 = sm;
  const float* sW2 = sm + 512;
  const float* sW3 = sm + 4608;
  const int lane = threadIdx.x & 63;
  const int gw = blockIdx.x * 16 + (threadIdx.x >> 6);
  const int rowoff = lane * 64;        // word offset of this lane's W2T/W3T row
  const int lsw = lane & 7;            // swizzle key

  for (int n = gw; n < kN; n += 256 * 16) {
    int tmp = 0;
    if (lane == 0) tmp = ends[n];
    else if (lane == 1) tmp = cnts[n];
    const int end = bcasti(tmp, 0);
    const int cn = bcasti(tmp, 1);
    float a0 = 0.f, axx = 0.f, ayy = 0.f, azz = 0.f;

    for (int base = end - cn; base < end; base += 64) {
      const int m = min(64, end - base);
      int sidv = 0;
      float4 r0v = make_float4(0.f, 0.f, 0.f, 0.f);
      float4 r1v = r0v, svv = r0v;
      if (lane < m) {
        const int e = eids[base + lane];
        sidv = ei[e];
        r0v = *(const float4*)(rb + (size_t)e * 8);
        r1v = *(const float4*)(rb + (size_t)e * 8 + 4);
        svv = *(const float4*)(sph + (size_t)e * 4);
      }
      const int sid0 = bcasti(sidv, 0);
      float4 h = hcomb[(size_t)sid0 * 64 + lane];

      for (int j = 0; j < m; ++j) {
        float4 hn = h;
        if (j + 1 < m) {
          const int sn = bcasti(sidv, j + 1);
          hn = hcomb[(size_t)sn * 64 + lane];
        }
        // broadcast edge scalars from the holder lane
        const float e0 = bcast(r0v.x, j), e1 = bcast(r0v.y, j);
        const float e2 = bcast(r0v.z, j), e3 = bcast(r0v.w, j);
        const float e4 = bcast(r1v.x, j), e5 = bcast(r1v.y, j);
        const float e6 = bcast(r1v.z, j), e7 = bcast(r1v.w, j);
        const float y0 = bcast(svv.x, j), y1 = bcast(svv.y, j);
        const float y2 = bcast(svv.z, j), y3 = bcast(svv.w, j);

        // layer 1 (8 -> 64), lane = hidden unit
        float acc = e0 * sW1[lane];
        acc = fmaf(e1, sW1[64 + lane], acc);
        acc = fmaf(e2, sW1[128 + lane], acc);
        acc = fmaf(e3, sW1[192 + lane], acc);
        acc = fmaf(e4, sW1[256 + lane], acc);
        acc = fmaf(e5, sW1[320 + lane], acc);
        acc = fmaf(e6, sW1[384 + lane], acc);
        acc = fmaf(e7, sW1[448 + lane], acc);
        const float h1 = silu(acc);

        // layer 2 (64 -> 64): b128 swizzled reads, readlane broadcast of h1
        float acc2 = 0.f;
#pragma unroll
        for (int k4 = 0; k4 < 16; ++k4) {
          const float4 w = *(const float4*)(sW2 + rowoff + ((k4 ^ lsw) << 2));
          acc2 = fmaf(bcast(h1, 4 * k4 + 0), w.x, acc2);
          acc2 = fmaf(bcast(h1, 4 * k4 + 1), w.y, acc2);
          acc2 = fmaf(bcast(h1, 4 * k4 + 2), w.z, acc2);
          acc2 = fmaf(bcast(h1, 4 * k4 + 3), w.w, acc2);
        }
        const float h2 = silu(acc2);

        // layer 3 (64 -> 5x64), lane = channel
        float w0 = 0.f, w1v = 0.f, w2v = 0.f, w3v = 0.f, w4v = 0.f;
#pragma unroll 4
        for (int k4 = 0; k4 < 16; ++k4) {
          const int off = rowoff + ((k4 ^ lsw) << 2);
          const float4 p0 = *(const float4*)(sW3 + off);
          const float4 p1 = *(const float4*)(sW3 + 4096 + off);
          const float4 p2 = *(const float4*)(sW3 + 8192 + off);
          const float4 p3 = *(const float4*)(sW3 + 12288 + off);
          const float4 p4 = *(const float4*)(sW3 + 16384 + off);
          const float k0 = bcast(h2, 4 * k4 + 0);
          const float k1 = bcast(h2, 4 * k4 + 1);
          const float k2 = bcast(h2, 4 * k4 + 2);
          const float k3 = bcast(h2, 4 * k4 + 3);
          w0 = fmaf(k0, p0.x, w0); w0 = fmaf(k1, p0.y, w0);
          w0 = fmaf(k2, p0.z, w0); w0 = fmaf(k3, p0.w, w0);
          w1v = fmaf(k0, p1.x, w1v); w1v = fmaf(k1, p1.y, w1v);
          w1v = fmaf(k2, p1.z, w1v); w1v = fmaf(k3, p1.w, w1v);
          w2v = fmaf(k0, p2.x, w2v); w2v = fmaf(k1, p2.y, w2v);
          w2v = fmaf(k2, p2.z, w2v); w2v = fmaf(k3, p2.w, w2v);
          w3v = fmaf(k0, p3.x, w3v); w3v = fmaf(k1, p3.y, w3v);
          w3v = fmaf(k2, p3.z, w3v); w3v = fmaf(k3, p3.w, w3v);
          w4v = fmaf(k0, p4.x, w4v); w4v = fmaf(k1, p4.y, w4v);
          w4v = fmaf(k2, p4.z, w4v); w4v = fmaf(k3, p4.w, w4v);
        }

        // message
        const float dot = h.y * y1 + h.z * y2 + h.w * y3;
        const float m0 = w0 * h.x * y0 + w1v * kInv3 * dot;
        const float cx = h.z * y3 - h.w * y2;
        const float cy = h.w * y1 - h.y * y3;
        const float cz = h.y * y2 - h.z * y1;
        const float t2 = w2v * h.x;
        const float c4 = w4v * kInv2;
        const float w3y0 = w3v * y0;
        a0 += m0;
        axx += t2 * y1 + w3y0 * h.y + c4 * cx;
        ayy += t2 * y2 + w3y0 * h.z + c4 * cy;
        azz += t2 * y3 + w3y0 * h.w + c4 * cz;
        h = hn;
      }
    }
    tcomb[(size_t)n * 64 + lane] = make_float4(a0, axx, ayy, azz);
  }
}

// ---------------------------------------------------------------------------
// K3a: self-connection einsums (8-k LDS-tiled chunks of the weight tensors).
// nf row loaded coalesced (float4) and redistributed via per-wave LDS.
// ---------------------------------------------------------------------------
__global__ __launch_bounds__(1024, 2) void k_sc(const float* __restrict__ nf,
                                                const float* __restrict__ attrs,
                                                const float* __restrict__ scW0,
                                                const float* __restrict__ scW1,
                                                float4* __restrict__ scout) {
  extern __shared__ float sm[];  // 10240 (weights) + 16*256 (staging) floats
  float* s0 = sm;
  float* s1 = sm + 5120;
  const int lane = threadIdx.x & 63, wid = threadIdx.x >> 6;
  float* sb = sm + 10240 + wid * 256;
  for (int nb = blockIdx.x * 16; nb < kN; nb += 512 * 16) {
    const int n = nb + wid;
    const bool act = (n < kN);
    float xr0 = 0.f, x1x = 0.f, x1y = 0.f, x1z = 0.f;
    float avl = 0.f;
    if (act) {
      const float4 rv = ((const float4*)nf)[(size_t)n * 64 + lane];
      *(float4*)&sb[lane * 4] = rv;
      xr0 = sb[lane];
      x1x = sb[64 + 3 * lane];
      x1y = sb[64 + 3 * lane + 1];
      x1z = sb[64 + 3 * lane + 2];
      if (lane < 10) avl = attrs[(size_t)n * 10 + lane];
    }
    float attrv[10];
#pragma unroll
    for (int a = 0; a < 10; ++a) attrv[a] = bcast(avl, a);
    float a0 = 0.f, axx = 0.f, ayy = 0.f, azz = 0.f;
    for (int ck = 0; ck < 8; ++ck) {
      __syncthreads();  // protect LDS from previous chunk's readers
      for (int i = threadIdx.x; i < 5120; i += 1024) {
        s0[i] = scW0[ck * 5120 + i];
        s1[i] = scW1[ck * 5120 + i];
      }
      __syncthreads();
      if (act) {
#pragma unroll
        for (int k = 0; k < 8; ++k) {
          const int kg = ck * 8 + k;
          const float x0k = bcast(xr0, kg);
          const float xxk = bcast(x1x, kg);
          const float xyk = bcast(x1y, kg);
          const float xzk = bcast(x1z, kg);
          float t0 = 0.f, t1 = 0.f;
#pragma unroll
          for (int a = 0; a < 10; ++a) {
            t0 = fmaf(attrv[a], s0[k * 640 + a * 64 + lane], t0);
            t1 = fmaf(attrv[a], s1[k * 640 + a * 64 + lane], t1);
          }
          a0 = fmaf(x0k, t0, a0);
          axx = fmaf(xxk, t1, axx);
          ayy = fmaf(xyk, t1, ayy);
          azz = fmaf(xzk, t1, azz);
        }
      }
    }
    if (act) scout[(size_t)n * 64 + lane] = make_float4(a0, axx, ayy, azz);
  }
}

// ---------------------------------------------------------------------------
// K3b: lin transforms, gated nonlinearity, + self-connection, fin transforms.
// Output row assembled in per-wave LDS, stored as 64 x float4 (contiguous 1KB).
// ---------------------------------------------------------------------------
__global__ __launch_bounds__(1024, 1) void k_post(
    const float* __restrict__ attrs,
    const float* __restrict__ lin0, const float* __restrict__ lin1,
    const float* __restrict__ c0w, const float* __restrict__ c1w,
    const float* __restrict__ fin0, const float* __restrict__ fin1,
    const float4* __restrict__ tcomb, const float4* __restrict__ scout,
    float4* __restrict__ out) {
  extern __shared__ float sm[];  // 16384 (weights) + 16*256 (staging) floats
  float* sl0 = sm;
  float* sl1 = sm + 4096;
  float* sf0 = sm + 8192;
  float* sf1 = sm + 12288;
  __shared__ float sc0[1920];  // c0_w (10,3,64)
  __shared__ float sc1[1280];  // c1_w (10,2,64)
  for (int i = threadIdx.x; i < 4096; i += 1024) {
    sl0[i] = lin0[i];
    sl1[i] = lin1[i];
    sf0[i] = fin0[i];
    sf1[i] = fin1[i];
  }
  for (int i = threadIdx.x; i < 1920; i += 1024) sc0[i] = c0w[i];
  for (int i = threadIdx.x; i < 1280; i += 1024) sc1[i] = c1w[i];
  __syncthreads();

  const int lane = threadIdx.x & 63;
  float* sb = sm + 16384 + (threadIdx.x >> 6) * 256;
  for (int n = blockIdx.x * 16 + (threadIdx.x >> 6); n < kN; n += 512 * 16) {
    const float4 t = tcomb[(size_t)n * 64 + lane];
    float avl = 0.f;
    if (lane < 10) avl = attrs[(size_t)n * 10 + lane];
    float b0 = 0.f, bx = 0.f, by = 0.f, bz = 0.f;
#pragma unroll
    for (int k = 0; k < 64; ++k) {
      const float w0 = sl0[k * 64 + lane];
      const float w1 = sl1[k * 64 + lane];
      b0 = fmaf(bcast(t.x, k), w0, b0);
      bx = fmaf(bcast(t.y, k), w1, bx);
      by = fmaf(bcast(t.z, k), w1, by);
      bz = fmaf(bcast(t.w, k), w1, bz);
    }
    float cw00 = 0.f, cw01 = 0.f, cw02 = 0.f, cw10 = 0.f, cw11 = 0.f;
#pragma unroll
    for (int a = 0; a < 10; ++a) {
      const float av = bcast(avl, a);
      cw00 = fmaf(av, sc0[a * 192 + lane], cw00);
      cw01 = fmaf(av, sc0[a * 192 + 64 + lane], cw01);
      cw02 = fmaf(av, sc0[a * 192 + 128 + lane], cw02);
      cw10 = fmaf(av, sc1[a * 128 + lane], cw10);
      cw11 = fmaf(av, sc1[a * 128 + 64 + lane], cw11);
    }
    const float4 sc = scout[(size_t)n * 64 + lane];
    const float o0 = cw00 * b0 + cw01 * b0 * b0 +
                     cw02 * (bx * bx + by * by + bz * bz) + sc.x;
    const float o1x = cw10 * bx + cw11 * b0 * bx + sc.y;
    const float o1y = cw10 * by + cw11 * b0 * by + sc.z;
    const float o1z = cw10 * bz + cw11 * b0 * bz + sc.w;
    float f0 = 0.f, fx = 0.f, fy = 0.f, fz = 0.f;
#pragma unroll
    for (int k = 0; k < 64; ++k) {
      const float w0 = sf0[k * 64 + lane];
      const float w1 = sf1[k * 64 + lane];
      f0 = fmaf(bcast(o0, k), w0, f0);
      fx = fmaf(bcast(o1x, k), w1, fx);
      fy = fmaf(bcast(o1y, k), w1, fy);
      fz = fmaf(bcast(o1z, k), w1, fz);
    }
    // assemble row in LDS, store fully coalesced (64 lanes x 16B = 1KB)
    sb[lane] = f0;
    sb[64 + 3 * lane] = fx;
    sb[64 + 3 * lane + 1] = fy;
    sb[64 + 3 * lane + 2] = fz;
    const float4 ov = *(const float4*)&sb[lane * 4];
    out[(size_t)n * 64 + lane] = ov;
  }
}

}  // namespace

extern "C" void kernel_launch(void* const* d_in, const int* in_sizes, int n_in,
                              void* d_out, int out_size, void* d_ws,
                              size_t ws_size, hipStream_t stream) {
  (void)in_sizes; (void)n_in; (void)out_size; (void)ws_size;
  const float* nf = (const float*)d_in[0];
  const float* attrs = (const float*)d_in[1];
  const float* sph = (const float*)d_in[2];
  const float* rb = (const float*)d_in[3];
  const int* ei = (const int*)d_in[4];
  const float* preW0 = (const float*)d_in[5];
  const float* preW1 = (const float*)d_in[6];
  const float* mW1 = (const float*)d_in[7];
  const float* mW2 = (const float*)d_in[8];
  const float* mW3 = (const float*)d_in[9];
  const float* lin0 = (const float*)d_in[10];
  const float* lin1 = (const float*)d_in[11];
  const float* c0w = (const float*)d_in[12];
  const float* c1w = (const float*)d_in[13];
  const float* scW0 = (const float*)d_in[14];
  const float* scW1 = (const float*)d_in[15];
  const float* fin0 = (const float*)d_in[16];
  const float* fin1 = (const float*)d_in[17];
  float4* out = (float4*)d_out;

  char* ws = (char*)d_ws;
  float4* hcomb = (float4*)ws;                    // 51.2MB (reused as scout)
  float4* tcomb = (float4*)(ws + 51200000);       // 51.2MB
  int* cnts = (int*)(ws + 102400000);             // 200KB
  int* starts = (int*)(ws + 102600000);           // 200KB (becomes ends)
  int* eids = (int*)(ws + 102800000);             // 3.2MB
  float4* scout = hcomb;  // safe: k_edge (last hcomb reader) precedes k_sc

  hipMemsetAsync(cnts, 0, kN * sizeof(int), stream);

  k_pre<<<(kN + 3) / 4, 256, 0, stream>>>(nf, preW0, preW1, hcomb);
  k_hist<<<(kE + 255) / 256, 256, 0, stream>>>(ei, cnts);
  k_scan<<<1, 1024, 0, stream>>>(cnts, starts);
  k_scatter<<<(kE + 255) / 256, 256, 0, stream>>>(ei, starts, eids);

  hipFuncSetAttribute((const void*)k_edge,
                      hipFuncAttributeMaxDynamicSharedMemorySize, 25088 * 4);
  k_edge<<<256, 1024, 25088 * 4, stream>>>(rb, sph, ei, eids, starts, cnts,
                                           mW1, mW2, mW3, hcomb, tcomb);

  hipFuncSetAttribute((const void*)k_sc,
                      hipFuncAttributeMaxDynamicSharedMemorySize, 14336 * 4);
  k_sc<<<512, 1024, 14336 * 4, stream>>>(nf, attrs, scW0, scW1, scout);

  hipFuncSetAttribute((const void*)k_post,
                      hipFuncAttributeMaxDynamicSharedMemorySize, 20480 * 4);
  k_post<<<512, 1024, 20480 * 4, stream>>>(attrs, lin0, lin1, c0w, c1w,
                                           fin0, fin1, tcomb, scout, out);
}